// Round 6
// baseline (357.366 us; speedup 1.0000x reference)
//
#include <hip/hip_runtime.h>
#include <hip/hip_cooperative_groups.h>
#include <math.h>

namespace cg = cooperative_groups;

// GCN 2-hop + linear(64->2) + log_softmax, N=100000, E=1600000, D=64.
//
// R5 lesson: 8 small dependent kernels = ~177us dominated by per-dispatch
// fixed costs (logical traffic only ~140MB ~= 22us at BW). This round fuses
// the whole pipeline into ONE persistent cooperative kernel with grid.sync()
// phase barriers. Same algorithm as R5 (projection-first C=2 features,
// bucketed LDS accumulation, no node-granular global scatters).

#define NODES 100000
#define EDGES 1600000
#define DIM 64

#define PBITS 12
#define PSIZE 4096
#define P_BUCKETS 25
#define CAP 131072
#define NSLICE 10
#define NBLOCKS (P_BUCKETS * NSLICE)  // 250 blocks
#define NT 1024                       // threads per block (16 waves)
#define NPB (NODES / NBLOCKS)         // 400 nodes per block
#define EPB (EDGES / NBLOCKS)         // 6400 edges per block (partition)
#define PPB (EPB / 2)                 // 3200 edge-pairs per block

// ===========================================================================
// THE fused cooperative kernel
// ===========================================================================
__global__ __launch_bounds__(NT) void gcn_all(
    const void* __restrict__ ei, const float* __restrict__ x,
    const float* __restrict__ W, const float* __restrict__ bias,
    float2* __restrict__ out, int* __restrict__ mode, int* __restrict__ cursor,
    int2* __restrict__ ecbuf, int* __restrict__ dpart,
    float* __restrict__ dinv, float2* __restrict__ ts, float2* __restrict__ z,
    float2* __restrict__ hpart) {
  cg::grid_group grid = cg::this_grid();
  __shared__ int shCnt[P_BUCKETS];
  __shared__ int shBase[P_BUCKETS];
  __shared__ int shHist[PSIZE];   // 16 KB (degree phase)
  __shared__ float shAx[PSIZE];   // 16 KB (hop accum)
  __shared__ float shAy[PSIZE];   // 16 KB

  const int b = blockIdx.x;
  const int t = threadIdx.x;

  // --- phase 0: mode detect (int64 vs int32 edge_index) + cursor init -----
  if (b == 0) {
    if (t < 64) {
      const int* p = (const int*)ei;
      unsigned long long ball = __ballot(p[2 * t + 1] == 0);
      if (t == 0) *mode = (ball == ~0ULL) ? 1 : 0;
    }
    if (t < P_BUCKETS) cursor[t] = t * CAP;
  }
  grid.sync();

  // --- phase 1: radix partition by target bucket ---------------------------
  {
    const int m = *mode;
    if (t < P_BUCKETS) shCnt[t] = 0;
    __syncthreads();
    const int pbase = b * PPB;
    if (m) {
      const longlong2* cp =
          (const longlong2*)((const long long*)ei + EDGES) + pbase;
      for (int i = t; i < PPB; i += NT) {
        longlong2 v = cp[i];
        atomicAdd(&shCnt[((int)v.x) >> PBITS], 1);
        atomicAdd(&shCnt[((int)v.y) >> PBITS], 1);
      }
    } else {
      const int2* cp = (const int2*)((const int*)ei + EDGES) + pbase;
      for (int i = t; i < PPB; i += NT) {
        int2 v = cp[i];
        atomicAdd(&shCnt[v.x >> PBITS], 1);
        atomicAdd(&shCnt[v.y >> PBITS], 1);
      }
    }
    __syncthreads();
    if (t < P_BUCKETS) {
      shBase[t] = atomicAdd(&cursor[t], shCnt[t]);
      shCnt[t] = 0;  // reuse as local rank cursor
    }
    __syncthreads();
    if (m) {
      const longlong2* rp = (const longlong2*)ei + pbase;
      const longlong2* cp =
          (const longlong2*)((const long long*)ei + EDGES) + pbase;
      for (int i = t; i < PPB; i += NT) {
        longlong2 rv = rp[i];
        longlong2 cv = cp[i];
        int c0 = (int)cv.x, b0 = c0 >> PBITS;
        int p0 = shBase[b0] + atomicAdd(&shCnt[b0], 1);
        if (p0 < (b0 + 1) * CAP)
          ecbuf[p0] = make_int2((int)rv.x, c0 & (PSIZE - 1));
        int c1 = (int)cv.y, b1 = c1 >> PBITS;
        int p1 = shBase[b1] + atomicAdd(&shCnt[b1], 1);
        if (p1 < (b1 + 1) * CAP)
          ecbuf[p1] = make_int2((int)rv.y, c1 & (PSIZE - 1));
      }
    } else {
      const int2* rp = (const int2*)ei + pbase;
      const int2* cp = (const int2*)((const int*)ei + EDGES) + pbase;
      for (int i = t; i < PPB; i += NT) {
        int2 rv = rp[i];
        int2 cv = cp[i];
        int b0 = cv.x >> PBITS;
        int p0 = shBase[b0] + atomicAdd(&shCnt[b0], 1);
        if (p0 < (b0 + 1) * CAP)
          ecbuf[p0] = make_int2(rv.x, cv.x & (PSIZE - 1));
        int b1 = cv.y >> PBITS;
        int p1 = shBase[b1] + atomicAdd(&shCnt[b1], 1);
        if (p1 < (b1 + 1) * CAP)
          ecbuf[p1] = make_int2(rv.y, cv.y & (PSIZE - 1));
      }
    }
  }
  grid.sync();

  // slice geometry for this block's (bucket, slice) role
  const int pb = b / NSLICE, sl = b % NSLICE;
  const int sbase = pb * CAP;
  const int scnt = min(cursor[pb] - sbase, CAP);
  const int sper = (scnt + NSLICE - 1) / NSLICE;
  const int sbeg = sbase + sl * sper;
  const int send = min(sbase + scnt, sbeg + sper);

  // --- phase 2: degree histogram partials ---------------------------------
  {
    for (int i = t; i < PSIZE; i += NT) shHist[i] = 0;
    __syncthreads();
    for (int e = sbeg + t; e < send; e += NT)
      atomicAdd(&shHist[ecbuf[e].y], 1);
    __syncthreads();
    int* op = dpart + (size_t)b * PSIZE;
    for (int i = t; i < PSIZE; i += NT) op[i] = shHist[i];
  }
  grid.sync();

  // --- phase 3: dinv merge + projection ts = dinv * (x @ W^T) -------------
  {
    const int nbase = b * NPB;
    if (t < NPB) {
      int i = nbase + t;
      int p = i >> PBITS, l = i & (PSIZE - 1);
      int d = 0;
#pragma unroll
      for (int s = 0; s < NSLICE; s++)
        d += dpart[(size_t)(p * NSLICE + s) * PSIZE + l];
      dinv[i] = rsqrtf((float)(d + 1));
    }
    __syncthreads();
    // projection: 4 nodes per wave, 16 lanes per node, float4 loads
    const int wave = t >> 6, lane = t & 63;
    const int g = lane >> 4, r = lane & 15;
    for (int k = wave * 4; k < NPB; k += (NT / 64) * 4) {
      int kk = k + g;
      if (kk < NPB) {
        int node = nbase + kk;
        float4 xv = *(const float4*)&x[(size_t)node * DIM + r * 4];
        float4 w0 = *(const float4*)&W[r * 4];
        float4 w1 = *(const float4*)&W[DIM + r * 4];
        float p0 = xv.x * w0.x + xv.y * w0.y + xv.z * w0.z + xv.w * w0.w;
        float p1 = xv.x * w1.x + xv.y * w1.y + xv.z * w1.z + xv.w * w1.w;
#pragma unroll
        for (int off = 8; off >= 1; off >>= 1) {
          p0 += __shfl_xor(p0, off, 16);
          p1 += __shfl_xor(p1, off, 16);
        }
        if (r == 0) {
          float di = dinv[node];
          ts[node] = make_float2(di * p0, di * p1);
        }
      }
    }
  }
  grid.sync();

  // --- phases 4-7: two hops (LDS segment-sum -> partials -> merge) --------
  for (int hop = 0; hop < 2; ++hop) {
    const float2* feat = hop ? z : ts;
    for (int i = t; i < PSIZE; i += NT) {
      shAx[i] = 0.f;
      shAy[i] = 0.f;
    }
    __syncthreads();
    for (int e = sbeg + t; e < send; e += NT) {
      int2 ec = ecbuf[e];
      float2 v = feat[ec.x];
      atomicAdd(&shAx[ec.y], v.x);
      atomicAdd(&shAy[ec.y], v.y);
    }
    __syncthreads();
    {
      float2* op = hpart + (size_t)b * PSIZE;
      for (int i = t; i < PSIZE; i += NT)
        op[i] = make_float2(shAx[i], shAy[i]);
    }
    grid.sync();
    // merge for this block's 400 nodes
    const int nbase = b * NPB;
    if (t < NPB) {
      int i = nbase + t;
      int p = i >> PBITS, l = i & (PSIZE - 1);
      float2 self = hop ? z[i] : ts[i];
      float ax = self.x, ay = self.y;
#pragma unroll
      for (int s = 0; s < NSLICE; s++) {
        float2 v = hpart[(size_t)(p * NSLICE + s) * PSIZE + l];
        ax += v.x;
        ay += v.y;
      }
      float di = dinv[i];
      if (hop == 0) {
        float sc = di * di;
        z[i] = make_float2(sc * ax, sc * ay);
      } else {
        float l0 = di * ax + bias[0];
        float l1 = di * ay + bias[1];
        float mm = fmaxf(l0, l1);
        float ls = mm + logf(expf(l0 - mm) + expf(l1 - mm));
        out[i] = make_float2(l0 - ls, l1 - ls);
      }
    }
    if (hop == 0) grid.sync();
  }
}

// ===========================================================================
// Fallback: the proven R5 multi-kernel pipeline (used only if cooperative
// launch is unavailable).
// ===========================================================================
#define FPART_BLOCKS 256
#define FSEG (EDGES / FPART_BLOCKS)
#define FPAIRS (FSEG / 2)

__global__ void fb_init(const void* ei, int* mode, int* cursor) {
  int t = threadIdx.x;
  const int* p = (const int*)ei;
  unsigned long long ball = __ballot(p[2 * t + 1] == 0);
  if (t == 0) *mode = (ball == ~0ULL) ? 1 : 0;
  if (t < P_BUCKETS) cursor[t] = t * CAP;
}

__global__ void fb_partition(const void* ei, const int* __restrict__ mode,
                             int* __restrict__ cursor, int2* __restrict__ ecbuf) {
  __shared__ int lcnt[P_BUCKETS];
  __shared__ int lbase[P_BUCKETS];
  int t = threadIdx.x;
  int m = *mode;
  int pbase = blockIdx.x * FPAIRS;
  if (t < P_BUCKETS) lcnt[t] = 0;
  __syncthreads();
  if (m) {
    const longlong2* cp = (const longlong2*)((const long long*)ei + EDGES) + pbase;
    for (int i = t; i < FPAIRS; i += 256) {
      longlong2 v = cp[i];
      atomicAdd(&lcnt[((int)v.x) >> PBITS], 1);
      atomicAdd(&lcnt[((int)v.y) >> PBITS], 1);
    }
  } else {
    const int2* cp = (const int2*)((const int*)ei + EDGES) + pbase;
    for (int i = t; i < FPAIRS; i += 256) {
      int2 v = cp[i];
      atomicAdd(&lcnt[v.x >> PBITS], 1);
      atomicAdd(&lcnt[v.y >> PBITS], 1);
    }
  }
  __syncthreads();
  if (t < P_BUCKETS) {
    lbase[t] = atomicAdd(&cursor[t], lcnt[t]);
    lcnt[t] = 0;
  }
  __syncthreads();
  if (m) {
    const longlong2* rp = (const longlong2*)ei + pbase;
    const longlong2* cp = (const longlong2*)((const long long*)ei + EDGES) + pbase;
    for (int i = t; i < FPAIRS; i += 256) {
      longlong2 rv = rp[i];
      longlong2 cv = cp[i];
      int c0 = (int)cv.x, b0 = c0 >> PBITS;
      int p0 = lbase[b0] + atomicAdd(&lcnt[b0], 1);
      if (p0 < (b0 + 1) * CAP) ecbuf[p0] = make_int2((int)rv.x, c0 & (PSIZE - 1));
      int c1 = (int)cv.y, b1 = c1 >> PBITS;
      int p1 = lbase[b1] + atomicAdd(&lcnt[b1], 1);
      if (p1 < (b1 + 1) * CAP) ecbuf[p1] = make_int2((int)rv.y, c1 & (PSIZE - 1));
    }
  } else {
    const int2* rp = (const int2*)ei + pbase;
    const int2* cp = (const int2*)((const int*)ei + EDGES) + pbase;
    for (int i = t; i < FPAIRS; i += 256) {
      int2 rv = rp[i];
      int2 cv = cp[i];
      int b0 = cv.x >> PBITS;
      int p0 = lbase[b0] + atomicAdd(&lcnt[b0], 1);
      if (p0 < (b0 + 1) * CAP) ecbuf[p0] = make_int2(rv.x, cv.x & (PSIZE - 1));
      int b1 = cv.y >> PBITS;
      int p1 = lbase[b1] + atomicAdd(&lcnt[b1], 1);
      if (p1 < (b1 + 1) * CAP) ecbuf[p1] = make_int2(rv.y, cv.y & (PSIZE - 1));
    }
  }
}

__global__ void fb_deg(const int* __restrict__ cursor,
                       const int2* __restrict__ ecbuf, float* __restrict__ dinv) {
  __shared__ int h[PSIZE];
  int p = blockIdx.x;
  for (int i = threadIdx.x; i < PSIZE; i += 1024) h[i] = 0;
  __syncthreads();
  int base = p * CAP;
  int cnt = min(cursor[p] - base, CAP);
  for (int e = threadIdx.x; e < cnt; e += 1024)
    atomicAdd(&h[ecbuf[base + e].y], 1);
  __syncthreads();
  int gbase = p << PBITS;
  for (int i = threadIdx.x; i < PSIZE; i += 1024) {
    int g = gbase + i;
    if (g < NODES) dinv[g] = rsqrtf((float)(h[i] + 1));
  }
}

__global__ void fb_proj(const float* __restrict__ x, const float* __restrict__ W,
                        const float* __restrict__ dinv, float2* __restrict__ ts) {
  int wid = (blockIdx.x * (blockDim.x >> 6)) + (threadIdx.x >> 6);
  int d = threadIdx.x & 63;
  if (wid >= NODES) return;
  float xv = x[(size_t)wid * DIM + d];
  float p0 = xv * W[d];
  float p1 = xv * W[DIM + d];
#pragma unroll
  for (int off = 32; off >= 1; off >>= 1) {
    p0 += __shfl_xor(p0, off, 64);
    p1 += __shfl_xor(p1, off, 64);
  }
  if (d == 0) {
    float di = dinv[wid];
    ts[wid] = make_float2(di * p0, di * p1);
  }
}

__global__ void fb_hop(const int* __restrict__ cursor,
                       const int2* __restrict__ ecbuf,
                       const float2* __restrict__ feat,
                       float2* __restrict__ hpart) {
  __shared__ float lx[PSIZE];
  __shared__ float ly[PSIZE];
  int p = blockIdx.x / NSLICE, s = blockIdx.x % NSLICE;
  for (int i = threadIdx.x; i < PSIZE; i += 512) {
    lx[i] = 0.f;
    ly[i] = 0.f;
  }
  __syncthreads();
  int base = p * CAP;
  int cnt = min(cursor[p] - base, CAP);
  int per = (cnt + NSLICE - 1) / NSLICE;
  int beg = base + s * per;
  int end = min(base + cnt, beg + per);
  for (int e = beg + threadIdx.x; e < end; e += 512) {
    int2 ec = ecbuf[e];
    float2 v = feat[ec.x];
    atomicAdd(&lx[ec.y], v.x);
    atomicAdd(&ly[ec.y], v.y);
  }
  __syncthreads();
  float2* outp = hpart + (size_t)blockIdx.x * PSIZE;
  for (int i = threadIdx.x; i < PSIZE; i += 512)
    outp[i] = make_float2(lx[i], ly[i]);
}

__global__ void fb_merge1(const float2* __restrict__ hpart,
                          const float2* __restrict__ ts,
                          const float* __restrict__ dinv, float2* __restrict__ z) {
  int i = blockIdx.x * blockDim.x + threadIdx.x;
  if (i >= NODES) return;
  int p = i >> PBITS, l = i & (PSIZE - 1);
  float2 t0 = ts[i];
  float ax = t0.x, ay = t0.y;
#pragma unroll
  for (int s = 0; s < NSLICE; s++) {
    float2 v = hpart[(size_t)(p * NSLICE + s) * PSIZE + l];
    ax += v.x;
    ay += v.y;
  }
  float di = dinv[i];
  float sc = di * di;
  z[i] = make_float2(sc * ax, sc * ay);
}

__global__ void fb_merge2(const float2* __restrict__ hpart,
                          const float2* __restrict__ z,
                          const float* __restrict__ dinv,
                          const float* __restrict__ bias,
                          float2* __restrict__ out) {
  int i = blockIdx.x * blockDim.x + threadIdx.x;
  if (i >= NODES) return;
  int p = i >> PBITS, l = i & (PSIZE - 1);
  float2 z0 = z[i];
  float ax = z0.x, ay = z0.y;
#pragma unroll
  for (int s = 0; s < NSLICE; s++) {
    float2 v = hpart[(size_t)(p * NSLICE + s) * PSIZE + l];
    ax += v.x;
    ay += v.y;
  }
  float di = dinv[i];
  float l0 = di * ax + bias[0];
  float l1 = di * ay + bias[1];
  float m = fmaxf(l0, l1);
  float ls = m + logf(expf(l0 - m) + expf(l1 - m));
  out[i] = make_float2(l0 - ls, l1 - ls);
}

// ===========================================================================
extern "C" void kernel_launch(void* const* d_in, const int* in_sizes, int n_in,
                              void* d_out, int out_size, void* d_ws,
                              size_t ws_size, hipStream_t stream) {
  const void* ei = d_in[1];
  const float* x = (const float*)d_in[0];
  const float* W = (const float*)d_in[2];
  const float* bias = (const float*)d_in[3];
  float2* out = (float2*)d_out;

  char* w = (char*)d_ws;
  size_t off = 0;
  auto alloc = [&](size_t bytes) -> char* {
    char* p = w + off;
    off += (bytes + 255) & ~(size_t)255;
    return p;
  };
  int* mode = (int*)alloc(sizeof(int));
  int* cursor = (int*)alloc(P_BUCKETS * sizeof(int));
  int2* ecbuf = (int2*)alloc((size_t)P_BUCKETS * CAP * sizeof(int2));  // 26MB
  int* dpart = (int*)alloc((size_t)NBLOCKS * PSIZE * sizeof(int));     // 4MB
  float* dinv = (float*)alloc(NODES * sizeof(float));
  float2* ts = (float2*)alloc(NODES * sizeof(float2));
  float2* z = (float2*)alloc(NODES * sizeof(float2));
  float2* hpart = (float2*)alloc((size_t)NBLOCKS * PSIZE * sizeof(float2));
  (void)ws_size;

  void* args[] = {(void*)&ei,    (void*)&x,     (void*)&W,     (void*)&bias,
                  (void*)&out,   (void*)&mode,  (void*)&cursor, (void*)&ecbuf,
                  (void*)&dpart, (void*)&dinv,  (void*)&ts,     (void*)&z,
                  (void*)&hpart};
  hipError_t err = hipLaunchCooperativeKernel(
      reinterpret_cast<void*>(gcn_all), dim3(NBLOCKS), dim3(NT), args, 0,
      stream);
  if (err != hipSuccess) {
    // fallback: proven R5 multi-kernel pipeline
    const int NGRID = (NODES + 255) / 256;
    fb_init<<<1, 64, 0, stream>>>(ei, mode, cursor);
    fb_partition<<<FPART_BLOCKS, 256, 0, stream>>>(ei, mode, cursor, ecbuf);
    fb_deg<<<P_BUCKETS, 1024, 0, stream>>>(cursor, ecbuf, dinv);
    const int WPB = 256 / 64;
    fb_proj<<<(NODES + WPB - 1) / WPB, 256, 0, stream>>>(x, W, dinv, ts);
    fb_hop<<<NBLOCKS, 512, 0, stream>>>(cursor, ecbuf, ts, hpart);
    fb_merge1<<<NGRID, 256, 0, stream>>>(hpart, ts, dinv, z);
    fb_hop<<<NBLOCKS, 512, 0, stream>>>(cursor, ecbuf, z, hpart);
    fb_merge2<<<NGRID, 256, 0, stream>>>(hpart, z, dinv, bias, out);
  }
}

// Round 8
// 154.199 us; speedup vs baseline: 2.3176x; 2.3176x over previous
//
#include <hip/hip_runtime.h>
#include <hip/hip_bf16.h>
#include <math.h>

// GCN 2-hop + linear(64->2) + log_softmax, N=100000, E=1600000, D=64.
//
// R6 lesson: cooperative grid.sync costs ~30us/sync on MI355X (non-coherent
// per-XCD L2s force cache writeback/invalidate) -> fused kernel was 278us of
// mostly stall. This round: back to plain kernels, but only 4 of them.
//
// Small buckets (256 nodes, 391 buckets): one block per bucket handles the
// whole bucket -> hop kernels write FINAL per-node results directly (no
// slice partials, no merge kernels, no hpart traffic). Edges packed into one
// int: (src << 8) | local_col. deg & proj are made independent (proj writes
// u = x@W^T, deg writes dinv; hop1 forms dinv*u on the fly from a float4
// gather) so they share one role-split kernel.
//
// Math (PyG gcn_norm with self-loops, dinv = rsqrt(indeg+1)):
//   z[i]   = dinv_i^2 * (dinv_i*u_i + sum_{e:col=i} dinv_src*u_src)
//   logit  = dinv_i   * (z_i + sum_{e:col=i} z_src) + b
//   out    = log_softmax(logit)

#define NODES 100000
#define EDGES 1600000
#define DIM 64

#define PBITS 8
#define PSIZE 256
#define P_BUCKETS 391  // ceil(100000/256)
#define CAP 8192       // edges per bucket capacity (mean 4092, ~64 sigma)

#define PART_BLOCKS 256
#define PART_EDGES (EDGES / PART_BLOCKS)  // 6250
#define PART_PAIRS (PART_EDGES / 2)       // 3125

#define PROJ_BLOCKS 782
#define NODES_PER_PROJ 128  // 782*128 = 100096 >= NODES

// ---------------------------------------------------------------------------
// Partition edges into 391 target buckets. cursor[] holds RELATIVE offsets
// (pre-zeroed by hipMemsetAsync). Mode (int64 vs int32 edge_index) detected
// inline per block from the first 64 values' odd words.
__global__ __launch_bounds__(256) void part_kernel(const void* __restrict__ ei,
                                                   int* __restrict__ cursor,
                                                   int* __restrict__ ecbuf) {
  __shared__ int shMode;
  __shared__ int lcnt[P_BUCKETS];
  __shared__ int lbase[P_BUCKETS];
  const int t = threadIdx.x;
  if (t < 64) {
    const int* p = (const int*)ei;
    unsigned long long ball = __ballot(p[2 * t + 1] == 0);
    if (t == 0) shMode = (ball == ~0ULL) ? 1 : 0;
  }
  for (int i = t; i < P_BUCKETS; i += 256) lcnt[i] = 0;
  __syncthreads();
  const int m = shMode;
  const int pbase = blockIdx.x * PART_PAIRS;

  // pass 1: count targets
  if (m) {
    const longlong2* cp =
        (const longlong2*)((const long long*)ei + EDGES) + pbase;
    for (int i = t; i < PART_PAIRS; i += 256) {
      longlong2 v = cp[i];
      atomicAdd(&lcnt[((int)v.x) >> PBITS], 1);
      atomicAdd(&lcnt[((int)v.y) >> PBITS], 1);
    }
  } else {
    const int2* cp = (const int2*)((const int*)ei + EDGES) + pbase;
    for (int i = t; i < PART_PAIRS; i += 256) {
      int2 v = cp[i];
      atomicAdd(&lcnt[v.x >> PBITS], 1);
      atomicAdd(&lcnt[v.y >> PBITS], 1);
    }
  }
  __syncthreads();
  // reserve per-bucket chunks (relative offsets)
  for (int i = t; i < P_BUCKETS; i += 256) {
    int c = lcnt[i];
    lbase[i] = c ? atomicAdd(&cursor[i], c) : 0;
    lcnt[i] = 0;  // reuse as local rank cursor
  }
  __syncthreads();

  // pass 2: write packed edges into reserved chunks
  if (m) {
    const longlong2* rp = (const longlong2*)ei + pbase;
    const longlong2* cp =
        (const longlong2*)((const long long*)ei + EDGES) + pbase;
    for (int i = t; i < PART_PAIRS; i += 256) {
      longlong2 rv = rp[i];
      longlong2 cv = cp[i];
      {
        int r = (int)rv.x, c = (int)cv.x, bk = c >> PBITS;
        int rel = lbase[bk] + atomicAdd(&lcnt[bk], 1);
        if (rel < CAP) ecbuf[bk * CAP + rel] = (r << PBITS) | (c & (PSIZE - 1));
      }
      {
        int r = (int)rv.y, c = (int)cv.y, bk = c >> PBITS;
        int rel = lbase[bk] + atomicAdd(&lcnt[bk], 1);
        if (rel < CAP) ecbuf[bk * CAP + rel] = (r << PBITS) | (c & (PSIZE - 1));
      }
    }
  } else {
    const int2* rp = (const int2*)ei + pbase;
    const int2* cp = (const int2*)((const int*)ei + EDGES) + pbase;
    for (int i = t; i < PART_PAIRS; i += 256) {
      int2 rv = rp[i];
      int2 cv = cp[i];
      {
        int bk = cv.x >> PBITS;
        int rel = lbase[bk] + atomicAdd(&lcnt[bk], 1);
        if (rel < CAP)
          ecbuf[bk * CAP + rel] = (rv.x << PBITS) | (cv.x & (PSIZE - 1));
      }
      {
        int bk = cv.y >> PBITS;
        int rel = lbase[bk] + atomicAdd(&lcnt[bk], 1);
        if (rel < CAP)
          ecbuf[bk * CAP + rel] = (rv.y << PBITS) | (cv.y & (PSIZE - 1));
      }
    }
  }
}

// ---------------------------------------------------------------------------
// Role-split kernel: blocks [0,391) = per-bucket degree -> uq.z = dinv;
// blocks [391,1173) = projection -> uq.xy = x[i] @ W^T (no dinv yet).
__global__ __launch_bounds__(256) void degproj_kernel(
    const int* __restrict__ cursor, const int* __restrict__ ecbuf,
    const float* __restrict__ x, const float* __restrict__ W,
    float4* __restrict__ uq) {
  const int b = blockIdx.x;
  const int t = threadIdx.x;
  if (b < P_BUCKETS) {
    __shared__ int h[PSIZE];
    h[t] = 0;
    __syncthreads();
    const int cnt = min(cursor[b], CAP);
    const int* ep = ecbuf + b * CAP;
    for (int e = t; e < cnt; e += 256) atomicAdd(&h[ep[e] & (PSIZE - 1)], 1);
    __syncthreads();
    const int node = (b << PBITS) + t;
    if (node < NODES) uq[node].z = rsqrtf((float)(h[t] + 1));
  } else {
    const int nbase = (b - P_BUCKETS) * NODES_PER_PROJ;
    const int lane16 = t & 15;  // feature quad within node
    const int sub = t >> 4;     // 16 node-slots per pass
    const float4 w0 = *(const float4*)&W[lane16 * 4];
    const float4 w1 = *(const float4*)&W[DIM + lane16 * 4];
    for (int k = sub; k < NODES_PER_PROJ; k += 16) {
      const int node = nbase + k;
      if (node < NODES) {  // uniform within each 16-lane group
        float4 xv = *(const float4*)&x[(size_t)node * DIM + lane16 * 4];
        float p0 = xv.x * w0.x + xv.y * w0.y + xv.z * w0.z + xv.w * w0.w;
        float p1 = xv.x * w1.x + xv.y * w1.y + xv.z * w1.z + xv.w * w1.w;
#pragma unroll
        for (int off = 8; off >= 1; off >>= 1) {
          p0 += __shfl_xor(p0, off, 16);
          p1 += __shfl_xor(p1, off, 16);
        }
        if (lane16 == 0) *(float2*)&uq[node] = make_float2(p0, p1);
      }
    }
  }
}

// ---------------------------------------------------------------------------
// Hop 1: one block per bucket. LDS-accumulate dinv_src*u_src over bucket
// edges (float4 gather), fold self + dinv^2, write final z.
__global__ __launch_bounds__(256) void hop1_kernel(
    const int* __restrict__ cursor, const int* __restrict__ ecbuf,
    const float4* __restrict__ uq, float2* __restrict__ z) {
  __shared__ float ax[PSIZE];
  __shared__ float ay[PSIZE];
  const int b = blockIdx.x;
  const int t = threadIdx.x;
  ax[t] = 0.f;
  ay[t] = 0.f;
  __syncthreads();
  const int cnt = min(cursor[b], CAP);
  const int* ep = ecbuf + b * CAP;
  for (int e = t; e < cnt; e += 256) {
    int pk = ep[e];
    float4 q = uq[pk >> PBITS];
    int l = pk & (PSIZE - 1);
    atomicAdd(&ax[l], q.z * q.x);
    atomicAdd(&ay[l], q.z * q.y);
  }
  __syncthreads();
  const int node = (b << PBITS) + t;
  if (node < NODES) {
    float4 q = uq[node];
    float d = q.z;
    float s = d * d;
    z[node] = make_float2(s * (ax[t] + d * q.x), s * (ay[t] + d * q.y));
  }
}

// ---------------------------------------------------------------------------
// Hop 2: same structure gathering z; fold bias + log_softmax, write out.
__global__ __launch_bounds__(256) void hop2_kernel(
    const int* __restrict__ cursor, const int* __restrict__ ecbuf,
    const float2* __restrict__ z, const float4* __restrict__ uq,
    const float* __restrict__ bias, float2* __restrict__ out) {
  __shared__ float ax[PSIZE];
  __shared__ float ay[PSIZE];
  const int b = blockIdx.x;
  const int t = threadIdx.x;
  ax[t] = 0.f;
  ay[t] = 0.f;
  __syncthreads();
  const int cnt = min(cursor[b], CAP);
  const int* ep = ecbuf + b * CAP;
  for (int e = t; e < cnt; e += 256) {
    int pk = ep[e];
    float2 v = z[pk >> PBITS];
    int l = pk & (PSIZE - 1);
    atomicAdd(&ax[l], v.x);
    atomicAdd(&ay[l], v.y);
  }
  __syncthreads();
  const int node = (b << PBITS) + t;
  if (node < NODES) {
    float d = uq[node].z;
    float2 zi = z[node];
    float l0 = d * (ax[t] + zi.x) + bias[0];
    float l1 = d * (ay[t] + zi.y) + bias[1];
    float m = fmaxf(l0, l1);
    float ls = m + logf(expf(l0 - m) + expf(l1 - m));
    out[node] = make_float2(l0 - ls, l1 - ls);
  }
}

// ---------------------------------------------------------------------------
extern "C" void kernel_launch(void* const* d_in, const int* in_sizes, int n_in,
                              void* d_out, int out_size, void* d_ws,
                              size_t ws_size, hipStream_t stream) {
  const float* x = (const float*)d_in[0];
  const void* ei = d_in[1];
  const float* W = (const float*)d_in[2];
  const float* bias = (const float*)d_in[3];
  float2* out = (float2*)d_out;

  char* w = (char*)d_ws;
  size_t off = 0;
  auto alloc = [&](size_t bytes) -> char* {
    char* p = w + off;
    off += (bytes + 255) & ~(size_t)255;
    return p;
  };
  int* cursor = (int*)alloc(P_BUCKETS * sizeof(int));
  int* ecbuf = (int*)alloc((size_t)P_BUCKETS * CAP * sizeof(int));  // 12.8 MB
  float4* uq = (float4*)alloc((size_t)(P_BUCKETS << PBITS) * sizeof(float4));
  float2* z = (float2*)alloc((size_t)NODES * sizeof(float2));
  (void)ws_size;

  hipMemsetAsync(cursor, 0, P_BUCKETS * sizeof(int), stream);
  part_kernel<<<PART_BLOCKS, 256, 0, stream>>>(ei, cursor, ecbuf);
  degproj_kernel<<<P_BUCKETS + PROJ_BLOCKS, 256, 0, stream>>>(cursor, ecbuf, x,
                                                              W, uq);
  hop1_kernel<<<P_BUCKETS, 256, 0, stream>>>(cursor, ecbuf, uq, z);
  hop2_kernel<<<P_BUCKETS, 256, 0, stream>>>(cursor, ecbuf, z, uq, bias, out);
}